// Round 8
// baseline (224.568 us; speedup 1.0000x reference)
//
#include <hip/hip_runtime.h>
#include <hip/hip_bf16.h>

typedef _Float16 f16_8 __attribute__((ext_vector_type(8)));
typedef _Float16 f16_4 __attribute__((ext_vector_type(4)));
typedef float f32x4 __attribute__((ext_vector_type(4)));

#define NNODES 113
#define NGRAPH 4096

// ---------------- ws layout (bytes), empirically-safe envelope [0, 11,608,064)
// All regions DISJOINT now (p shrunk to fp16 freed 4 MB).
#define Z_OFF    0u            // 4096*128*4 = 2,097,152        [k1 -> k2]
#define PH_OFF   2097152u      // 4096*512*2 = 4,194,304 (fp16) [k2 -> k4]
#define PSUM_OFF 6291456u      // 256*512*4 = 524,288           [k2 -> k3]
#define PSQ_OFF  6815744u      // 256*512*4 = 524,288           [k2 -> k3]
#define GC_OFF   10485760u     // 128*4                         [k0 -> k1]
#define SA_OFF   10489856u     // 512*4                         [k3 -> k4]
#define SD_OFF   10491904u     // 512*4                         [k3 -> k4]
#define W2P_OFF  10493952u     // 16384*2 fp16                  [k0 -> k1]
#define W4P_OFF  10559488u     // 524288*2 fp16 -> end 11,608,064 [k0 -> k4]

// K0: blocks 0..255: W4 -> fp16 B-frag pack via LDS transpose;
// 256..263: W2 pack; 264: GN quadform consts.
// B-frag: elem ((kt*NT+nt)*64+L)*8+j <= W[k][n], k=kt*32+(L>>4)*8+j, n=nt*16+(L&15)
__global__ __launch_bounds__(256) void k0_prep(
    const float* __restrict__ W2, const float* __restrict__ W4,
    const float* __restrict__ W1, const float* __restrict__ b1,
    _Float16* __restrict__ w2p, _Float16* __restrict__ w4p,
    float* __restrict__ gc) {
  int b = blockIdx.x, t = threadIdx.x;
  if (b < 256) {                    // W4 tile: 32 k-rows x 64 n-cols
    __shared__ _Float16 T[32 * 72];
    int kt = b >> 4, nc = b & 15;
    int row = t >> 3, c8 = (t & 7) * 8;
    const float* src = &W4[(kt * 32 + row) * 1024 + nc * 64 + c8];
    float4 a0 = *(const float4*)src;
    float4 a1 = *(const float4*)(src + 4);
    f16_8 v = {(_Float16)a0.x, (_Float16)a0.y, (_Float16)a0.z, (_Float16)a0.w,
               (_Float16)a1.x, (_Float16)a1.y, (_Float16)a1.z, (_Float16)a1.w};
    *(f16_8*)&T[row * 72 + c8] = v;
    __syncthreads();
    int ntl = t >> 6, L = t & 63;
    f16_8 w;
#pragma unroll
    for (int j = 0; j < 8; j++)
      w[j] = T[((L >> 4) * 8 + j) * 72 + ntl * 16 + (L & 15)];
    *(f16_8*)&w4p[((kt * 64 + nc * 4 + ntl) * 64 + L) * 8] = w;
  } else if (b < 264) {             // W2 pack
    int q0 = (b - 256) * 256 + t;
    int L = q0 & 63, nt = (q0 >> 6) & 7, kt = q0 >> 9;
    f16_8 v;
#pragma unroll
    for (int j = 0; j < 8; j++)
      v[j] = (_Float16)W2[(kt * 32 + ((L >> 4) << 3) + j) * 128 + (nt << 4) + (L & 15)];
    *(f16_8*)&w2p[((kt * 8 + nt) * 64 + L) * 8] = v;
  } else {                          // GN quadform consts
    if (t < 128) {
      float a0 = W1[t], a1 = W1[128 + t], a2 = W1[256 + t], bb = b1[t];
      float p[14] = {a0, a1, a2, bb,
                     a0 * a0, 2.f * a0 * a1, 2.f * a0 * a2,
                     a1 * a1, 2.f * a1 * a2, a2 * a2,
                     2.f * bb * a0, 2.f * bb * a1, 2.f * bb * a2, bb * bb};
#pragma unroll
      for (int m = 1; m < 16; m <<= 1)
#pragma unroll
        for (int k = 0; k < 14; k++) p[k] += __shfl_xor(p[k], m, 64);
      if ((t & 15) == 0) {
        int gg = t >> 4;
#pragma unroll
        for (int k = 0; k < 4; k++) gc[gg * 16 + k] = p[k] * 0.0625f;
#pragma unroll
        for (int k = 4; k < 14; k++) gc[gg * 16 + k] = p[k];
      }
    }
  }
}

// K1: per-graph node net + max pool. Stats merged into fill (octet's 8 channels
// share one GN group -> inline fp32 quadform), 2 barriers, fp16 MFMA.
__global__ __launch_bounds__(256, 4) void k1_nodenet(
    const float* __restrict__ x, const float* __restrict__ roi,
    const float* __restrict__ W1, const float* __restrict__ b1,
    const float* __restrict__ gn_g, const float* __restrict__ gn_b,
    const _Float16* __restrict__ w2p, const float* __restrict__ b2,
    const float* __restrict__ gc, float* __restrict__ z) {
  __shared__ float4 xs4[NNODES];
  __shared__ _Float16 A[128 * 136];   // pitch 136 fp16 = 272 B
  int t = threadIdx.x, g = blockIdx.x;
  int lane = t & 63, wv = t >> 6, quad = lane >> 4, l16 = lane & 15;

  // this thread's fill octet o and its GN group gq = o>>1 (fixed per thread)
  int o = t & 15;
  int gq = o >> 1;
  float gcv[14];
#pragma unroll
  for (int j = 0; j < 14; j++) gcv[j] = gc[gq * 16 + j];

  float pw0[8], pw1[8], pw2[8], pb[8], pg[8], pbe[8];
#pragma unroll
  for (int j = 0; j < 8; j++) {
    int c = o * 8 + j;
    pw0[j] = W1[c]; pw1[j] = W1[128 + c]; pw2[j] = W1[256 + c];
    pb[j] = b1[c];  pg[j] = gn_g[c];      pbe[j] = gn_b[c];
  }

  f16_8 bh[4][2];
#pragma unroll
  for (int kt = 0; kt < 4; kt++)
#pragma unroll
    for (int ni = 0; ni < 2; ni++)
      bh[kt][ni] = *(const f16_8*)&w2p[((kt * 8 + wv * 2 + ni) * 64 + lane) * 8];

  for (int i = t; i < NNODES * 3; i += 256) {
    float v = x[g * (NNODES * 3) + i] * roi[i];
    ((float*)xs4)[(i / 3) * 4 + (i % 3)] = v;
  }
  __syncthreads();

  // fill A: 2048 items = 128 rows x 16 octets; inline quadform stats
  for (int it = t; it < 2048; it += 256) {
    int n = it >> 4;
    f16_8 hv;
    if (n < NNODES) {
      float4 xv = xs4[n];
      float mu = fmaf(xv.z, gcv[2], fmaf(xv.y, gcv[1], fmaf(xv.x, gcv[0], gcv[3])));
      float qf = fmaf(xv.z, gcv[12], fmaf(xv.y, gcv[11], fmaf(xv.x, gcv[10], gcv[13])));
      float u0 = fmaf(xv.z, gcv[6], fmaf(xv.y, gcv[5], xv.x * gcv[4]));
      qf = fmaf(xv.x, u0, qf);
      float u1 = fmaf(xv.z, gcv[8], xv.y * gcv[7]);
      qf = fmaf(xv.y, u1, qf);
      qf = fmaf(xv.z * xv.z, gcv[9], qf);
      float var = fmaxf(qf * 0.0625f - mu * mu, 0.0f);
      float ia = rsqrtf(var + 1e-5f);
      float ib = -mu * ia;
#pragma unroll
      for (int j = 0; j < 8; j++) {
        float h = fmaf(xv.z, pw2[j], fmaf(xv.y, pw1[j], fmaf(xv.x, pw0[j], pb[j])));
        float y = fmaf(fmaf(h, ia, ib), pg[j], pbe[j]);
        y = (y > 0.0f) ? y : 0.2f * y;
        hv[j] = (_Float16)y;
      }
    } else {
#pragma unroll
      for (int j = 0; j < 8; j++) hv[j] = (_Float16)0.f;
    }
    *(f16_8*)&A[n * 136 + o * 8] = hv;
  }
  __syncthreads();

  f32x4 acc[2][8];
#pragma unroll
  for (int a = 0; a < 2; a++)
#pragma unroll
    for (int m = 0; m < 8; m++) acc[a][m] = (f32x4){0.f, 0.f, 0.f, 0.f};

#pragma unroll
  for (int kt = 0; kt < 4; kt++) {
    f16_8 ah[8];
#pragma unroll
    for (int mt = 0; mt < 8; mt++)
      ah[mt] = *(const f16_8*)&A[(mt * 16 + l16) * 136 + kt * 32 + quad * 8];
#pragma unroll
    for (int ni = 0; ni < 2; ni++)
#pragma unroll
      for (int mt = 0; mt < 8; mt++)
        acc[ni][mt] = __builtin_amdgcn_mfma_f32_16x16x32_f16(ah[mt], bh[kt][ni], acc[ni][mt], 0, 0, 0);
  }

#pragma unroll
  for (int ni = 0; ni < 2; ni++) {
    int nt = wv * 2 + ni;
    float m = -3.4e38f;
#pragma unroll
    for (int mt = 0; mt < 8; mt++)
#pragma unroll
      for (int r = 0; r < 4; r++) {
        int row = mt * 16 + quad * 4 + r;
        if (row < NNODES) m = fmaxf(m, acc[ni][mt][r]);
      }
    m = fmaxf(m, __shfl_xor(m, 16, 64));
    m = fmaxf(m, __shfl_xor(m, 32, 64));
    if (quad == 0) {
      int col = nt * 16 + l16;
      z[g * 128 + col] = m + b2[col];
    }
  }
}

// K2: p = z @ W3 + b3 -> fp16 ph; fused deterministic per-block BN partials.
// 1024 blocks (rb256 x cb4), 16 rows x 128 cols; thread: 2 rows x 4 cols.
__global__ __launch_bounds__(256) void k2_proj(
    const float* __restrict__ z, const float* __restrict__ W3,
    const float* __restrict__ b3, _Float16* __restrict__ ph,
    float* __restrict__ psum, float* __restrict__ psq) {
  __shared__ float zs[16 * 128];
  __shared__ float reds[8 * 128];
  __shared__ float redq[8 * 128];
  int t = threadIdx.x;
  int rb = blockIdx.x >> 2, cbb = blockIdx.x & 3;
  int gr0 = rb * 16, cc0 = cbb * 128;
  for (int i = t; i < 2048; i += 256) zs[i] = z[gr0 * 128 + i];
  int cg = t & 31, rg = t >> 5;
  int cc = cc0 + cg * 4;
  float4 bb = *(const float4*)&b3[cc];
  float a0[4] = {0.f, 0.f, 0.f, 0.f}, a1[4] = {0.f, 0.f, 0.f, 0.f};
  __syncthreads();

#pragma unroll 8
  for (int k = 0; k < 128; k++) {
    float4 w = *(const float4*)&W3[k * 512 + cc];
    float z0 = zs[rg * 256 + k];
    float z1 = zs[rg * 256 + 128 + k];
    a0[0] = fmaf(z0, w.x, a0[0]); a0[1] = fmaf(z0, w.y, a0[1]);
    a0[2] = fmaf(z0, w.z, a0[2]); a0[3] = fmaf(z0, w.w, a0[3]);
    a1[0] = fmaf(z1, w.x, a1[0]); a1[1] = fmaf(z1, w.y, a1[1]);
    a1[2] = fmaf(z1, w.z, a1[2]); a1[3] = fmaf(z1, w.w, a1[3]);
  }
  int r0 = gr0 + rg * 2;
  f16_4 h0, h1;
  float s[4], q[4];
#pragma unroll
  for (int j = 0; j < 4; j++) {
    float v0 = a0[j] + ((float*)&bb)[j];
    float v1 = a1[j] + ((float*)&bb)[j];
    h0[j] = (_Float16)v0; h1[j] = (_Float16)v1;
    s[j] = v0 + v1;
    q[j] = fmaf(v0, v0, v1 * v1);
  }
  *(f16_4*)&ph[r0 * 512 + cc] = h0;
  *(f16_4*)&ph[(r0 + 1) * 512 + cc] = h1;
#pragma unroll
  for (int j = 0; j < 4; j++) {
    reds[rg * 128 + cg * 4 + j] = s[j];
    redq[rg * 128 + cg * 4 + j] = q[j];
  }
  __syncthreads();
  if (t < 128) {
    float ss = 0.f, qq = 0.f;
#pragma unroll
    for (int r = 0; r < 8; r++) { ss += reds[r * 128 + t]; qq += redq[r * 128 + t]; }
    psum[rb * 512 + cc0 + t] = ss;
    psq[rb * 512 + cc0 + t] = qq;
  }
}

// K3: fixed-order reduce of 256 partials -> BN scale a, shift d
__global__ __launch_bounds__(512) void k3_stats(
    const float* __restrict__ psum, const float* __restrict__ psq,
    const float* __restrict__ bn_g, const float* __restrict__ bn_b,
    float* __restrict__ sa, float* __restrict__ sd) {
  int c = threadIdx.x;
  float s = 0.f, q = 0.f;
#pragma unroll 8
  for (int b = 0; b < 256; b++) {
    s += psum[b * 512 + c];
    q += psq[b * 512 + c];
  }
  float mu = s * (1.0f / 4096.0f);
  float var = fmaxf(q * (1.0f / 4096.0f) - mu * mu, 0.0f);
  float sc = bn_g[c] * rsqrtf(var + 1e-5f);
  sa[c] = sc;
  sd[c] = bn_b[c] - mu * sc;
}

// K4: out = L2norm( relu(ph*a+d) @ W4 + b4 ). 256 blocks x 16 rows x 1024 cols.
// Full A-tile staged once (BN+ReLU+fp16), kt-loop streams w4p from XCD-L2,
// row-norm in-register, normalized store. Replaces k4a+k4b+psn.
__global__ __launch_bounds__(256) void k4_final(
    const _Float16* __restrict__ ph, const float* __restrict__ sa,
    const float* __restrict__ sd, const _Float16* __restrict__ w4p,
    const float* __restrict__ b4, float* __restrict__ out) {
  __shared__ _Float16 T[16 * 520];
  __shared__ float sas[512], sds[512];
  __shared__ float rred[64];
  int t = threadIdx.x;
  int gr0 = blockIdx.x * 16;
  int lane = t & 63, wv = t >> 6, quad = lane >> 4, l16 = lane & 15;

  for (int i = t; i < 512; i += 256) { sas[i] = sa[i]; sds[i] = sd[i]; }
  __syncthreads();

  {
    int row = t >> 4, seg = t & 15;
    const _Float16* src = &ph[(gr0 + row) * 512 + seg * 32];
#pragma unroll
    for (int c4 = 0; c4 < 4; c4++) {
      f16_8 pv = *(const f16_8*)&src[c4 * 8];
      f16_8 tv;
#pragma unroll
      for (int j = 0; j < 8; j++) {
        int k = seg * 32 + c4 * 8 + j;
        float v = fmaf((float)pv[j], sas[k], sds[k]);
        tv[j] = (_Float16)fmaxf(v, 0.0f);
      }
      *(f16_8*)&T[row * 520 + seg * 32 + c4 * 8] = tv;
    }
  }
  __syncthreads();

  f32x4 acc[16];
#pragma unroll
  for (int ni = 0; ni < 16; ni++) acc[ni] = (f32x4){0.f, 0.f, 0.f, 0.f};

  for (int kt = 0; kt < 16; kt++) {
    f16_8 af = *(const f16_8*)&T[l16 * 520 + kt * 32 + quad * 8];
#pragma unroll
    for (int ni = 0; ni < 16; ni++) {
      f16_8 bf = *(const f16_8*)&w4p[((kt * 64 + wv * 16 + ni) * 64 + lane) * 8];
      acc[ni] = __builtin_amdgcn_mfma_f32_16x16x32_f16(af, bf, acc[ni], 0, 0, 0);
    }
  }

  float rsq[4] = {0.f, 0.f, 0.f, 0.f};
#pragma unroll
  for (int ni = 0; ni < 16; ni++) {
    int col = wv * 256 + ni * 16 + l16;
    float bv = b4[col];
#pragma unroll
    for (int r = 0; r < 4; r++) {
      float v = acc[ni][r] + bv;
      acc[ni][r] = v;
      rsq[r] = fmaf(v, v, rsq[r]);
    }
  }
#pragma unroll
  for (int m = 1; m < 16; m <<= 1)
#pragma unroll
    for (int r = 0; r < 4; r++) rsq[r] += __shfl_xor(rsq[r], m, 64);
  if (l16 == 0) {
#pragma unroll
    for (int r = 0; r < 4; r++) rred[wv * 16 + quad * 4 + r] = rsq[r];
  }
  __syncthreads();

  float inv[4];
#pragma unroll
  for (int r = 0; r < 4; r++) {
    int row = quad * 4 + r;
    float ss = rred[row] + rred[16 + row] + rred[32 + row] + rred[48 + row];
    inv[r] = 1.0f / fmaxf(sqrtf(ss), 1e-12f);
  }
#pragma unroll
  for (int ni = 0; ni < 16; ni++) {
    int col = wv * 256 + ni * 16 + l16;
#pragma unroll
    for (int r = 0; r < 4; r++)
      out[(gr0 + quad * 4 + r) * 1024 + col] = acc[ni][r] * inv[r];
  }
}

extern "C" void kernel_launch(void* const* d_in, const int* in_sizes, int n_in,
                              void* d_out, int out_size, void* d_ws, size_t ws_size,
                              hipStream_t stream) {
  const float* x   = (const float*)d_in[0];
  const float* roi = (const float*)d_in[1];
  const float* W1  = (const float*)d_in[2];
  const float* b1  = (const float*)d_in[3];
  const float* gng = (const float*)d_in[4];
  const float* gnb = (const float*)d_in[5];
  const float* W2  = (const float*)d_in[6];
  const float* b2  = (const float*)d_in[7];
  const float* W3  = (const float*)d_in[8];
  const float* b3  = (const float*)d_in[9];
  const float* bng = (const float*)d_in[10];
  const float* bnb = (const float*)d_in[11];
  const float* W4  = (const float*)d_in[12];
  const float* b4  = (const float*)d_in[13];
  float* out = (float*)d_out;

  char* ws = (char*)d_ws;
  float*    z    = (float*)(ws + Z_OFF);
  _Float16* ph   = (_Float16*)(ws + PH_OFF);
  float*    psum = (float*)(ws + PSUM_OFF);
  float*    psq  = (float*)(ws + PSQ_OFF);
  float*    gc   = (float*)(ws + GC_OFF);
  float*    sa   = (float*)(ws + SA_OFF);
  float*    sd   = (float*)(ws + SD_OFF);
  _Float16* w2p  = (_Float16*)(ws + W2P_OFF);
  _Float16* w4p  = (_Float16*)(ws + W4P_OFF);

  k0_prep<<<265, 256, 0, stream>>>(W2, W4, W1, b1, w2p, w4p, gc);
  k1_nodenet<<<NGRAPH, 256, 0, stream>>>(x, roi, W1, b1, gng, gnb, w2p, b2, gc, z);
  k2_proj<<<1024, 256, 0, stream>>>(z, W3, b3, ph, psum, psq);
  k3_stats<<<1, 512, 0, stream>>>(psum, psq, bng, bnb, sa, sd);
  k4_final<<<256, 256, 0, stream>>>(ph, sa, sd, w4p, b4, out);
}

// Round 9
// 175.706 us; speedup vs baseline: 1.2781x; 1.2781x over previous
//
#include <hip/hip_runtime.h>
#include <hip/hip_bf16.h>

typedef _Float16 f16_8 __attribute__((ext_vector_type(8)));
typedef _Float16 f16_4 __attribute__((ext_vector_type(4)));
typedef float f32x4 __attribute__((ext_vector_type(4)));

#define NNODES 113
#define NGRAPH 4096

// ---------------- ws layout (bytes), empirically-safe envelope [0, 11,608,064)
// All regions disjoint.
#define Z_OFF    0u            // 4096*128*4 = 2,097,152        [k1 -> k2]
#define PH_OFF   2097152u      // 4096*512*2 = 4,194,304 (fp16) [k2 -> k4a]
#define PSUM_OFF 6291456u      // 256*512*4 = 524,288           [k2 -> k3]
#define PSQ_OFF  6815744u      // 256*512*4 = 524,288           [k2 -> k3]
#define PSN_OFF  7340032u      // 8*4096*4 = 131,072            [k4a -> k4b]
#define GC_OFF   10485760u     // 128*4                         [k0 -> k1]
#define SA_OFF   10489856u     // 512*4                         [k3 -> k4a]
#define SD_OFF   10491904u     // 512*4                         [k3 -> k4a]
#define W2P_OFF  10493952u     // 16384*2 fp16                  [k0 -> k1]
#define W4P_OFF  10559488u     // 524288*2 fp16 -> end 11,608,064 [k0 -> k4a]

// K0: blocks 0..255: W4 -> fp16 B-frag pack via LDS transpose;
// 256..263: W2 pack; 264: GN quadform consts.
// B-frag: elem ((kt*NT+nt)*64+L)*8+j <= W[k][n], k=kt*32+(L>>4)*8+j, n=nt*16+(L&15)
__global__ __launch_bounds__(256) void k0_prep(
    const float* __restrict__ W2, const float* __restrict__ W4,
    const float* __restrict__ W1, const float* __restrict__ b1,
    _Float16* __restrict__ w2p, _Float16* __restrict__ w4p,
    float* __restrict__ gc) {
  int b = blockIdx.x, t = threadIdx.x;
  if (b < 256) {                    // W4 tile: 32 k-rows x 64 n-cols
    __shared__ _Float16 T[32 * 72];
    int kt = b >> 4, nc = b & 15;
    int row = t >> 3, c8 = (t & 7) * 8;
    const float* src = &W4[(kt * 32 + row) * 1024 + nc * 64 + c8];
    float4 a0 = *(const float4*)src;
    float4 a1 = *(const float4*)(src + 4);
    f16_8 v = {(_Float16)a0.x, (_Float16)a0.y, (_Float16)a0.z, (_Float16)a0.w,
               (_Float16)a1.x, (_Float16)a1.y, (_Float16)a1.z, (_Float16)a1.w};
    *(f16_8*)&T[row * 72 + c8] = v;
    __syncthreads();
    int ntl = t >> 6, L = t & 63;
    f16_8 w;
#pragma unroll
    for (int j = 0; j < 8; j++)
      w[j] = T[((L >> 4) * 8 + j) * 72 + ntl * 16 + (L & 15)];
    *(f16_8*)&w4p[((kt * 64 + nc * 4 + ntl) * 64 + L) * 8] = w;
  } else if (b < 264) {             // W2 pack
    int q0 = (b - 256) * 256 + t;
    int L = q0 & 63, nt = (q0 >> 6) & 7, kt = q0 >> 9;
    f16_8 v;
#pragma unroll
    for (int j = 0; j < 8; j++)
      v[j] = (_Float16)W2[(kt * 32 + ((L >> 4) << 3) + j) * 128 + (nt << 4) + (L & 15)];
    *(f16_8*)&w2p[((kt * 8 + nt) * 64 + L) * 8] = v;
  } else {                          // GN quadform consts
    if (t < 128) {
      float a0 = W1[t], a1 = W1[128 + t], a2 = W1[256 + t], bb = b1[t];
      float p[14] = {a0, a1, a2, bb,
                     a0 * a0, 2.f * a0 * a1, 2.f * a0 * a2,
                     a1 * a1, 2.f * a1 * a2, a2 * a2,
                     2.f * bb * a0, 2.f * bb * a1, 2.f * bb * a2, bb * bb};
#pragma unroll
      for (int m = 1; m < 16; m <<= 1)
#pragma unroll
        for (int k = 0; k < 14; k++) p[k] += __shfl_xor(p[k], m, 64);
      if ((t & 15) == 0) {
        int gg = t >> 4;
#pragma unroll
        for (int k = 0; k < 4; k++) gc[gg * 16 + k] = p[k] * 0.0625f;
#pragma unroll
        for (int k = 4; k < 14; k++) gc[gg * 16 + k] = p[k];
      }
    }
  }
}

// K1: per-graph node net + max pool. Stats merged into fill (octet's 8 channels
// share one GN group -> inline fp32 quadform), 2 barriers, fp16 MFMA.
__global__ __launch_bounds__(256, 4) void k1_nodenet(
    const float* __restrict__ x, const float* __restrict__ roi,
    const float* __restrict__ W1, const float* __restrict__ b1,
    const float* __restrict__ gn_g, const float* __restrict__ gn_b,
    const _Float16* __restrict__ w2p, const float* __restrict__ b2,
    const float* __restrict__ gc, float* __restrict__ z) {
  __shared__ float4 xs4[NNODES];
  __shared__ _Float16 A[128 * 136];   // pitch 136 fp16 = 272 B
  int t = threadIdx.x, g = blockIdx.x;
  int lane = t & 63, wv = t >> 6, quad = lane >> 4, l16 = lane & 15;

  int o = t & 15;
  int gq = o >> 1;
  float gcv[14];
#pragma unroll
  for (int j = 0; j < 14; j++) gcv[j] = gc[gq * 16 + j];

  float pw0[8], pw1[8], pw2[8], pb[8], pg[8], pbe[8];
#pragma unroll
  for (int j = 0; j < 8; j++) {
    int c = o * 8 + j;
    pw0[j] = W1[c]; pw1[j] = W1[128 + c]; pw2[j] = W1[256 + c];
    pb[j] = b1[c];  pg[j] = gn_g[c];      pbe[j] = gn_b[c];
  }

  f16_8 bh[4][2];
#pragma unroll
  for (int kt = 0; kt < 4; kt++)
#pragma unroll
    for (int ni = 0; ni < 2; ni++)
      bh[kt][ni] = *(const f16_8*)&w2p[((kt * 8 + wv * 2 + ni) * 64 + lane) * 8];

  for (int i = t; i < NNODES * 3; i += 256) {
    float v = x[g * (NNODES * 3) + i] * roi[i];
    ((float*)xs4)[(i / 3) * 4 + (i % 3)] = v;
  }
  __syncthreads();

  for (int it = t; it < 2048; it += 256) {
    int n = it >> 4;
    f16_8 hv;
    if (n < NNODES) {
      float4 xv = xs4[n];
      float mu = fmaf(xv.z, gcv[2], fmaf(xv.y, gcv[1], fmaf(xv.x, gcv[0], gcv[3])));
      float qf = fmaf(xv.z, gcv[12], fmaf(xv.y, gcv[11], fmaf(xv.x, gcv[10], gcv[13])));
      float u0 = fmaf(xv.z, gcv[6], fmaf(xv.y, gcv[5], xv.x * gcv[4]));
      qf = fmaf(xv.x, u0, qf);
      float u1 = fmaf(xv.z, gcv[8], xv.y * gcv[7]);
      qf = fmaf(xv.y, u1, qf);
      qf = fmaf(xv.z * xv.z, gcv[9], qf);
      float var = fmaxf(qf * 0.0625f - mu * mu, 0.0f);
      float ia = rsqrtf(var + 1e-5f);
      float ib = -mu * ia;
#pragma unroll
      for (int j = 0; j < 8; j++) {
        float h = fmaf(xv.z, pw2[j], fmaf(xv.y, pw1[j], fmaf(xv.x, pw0[j], pb[j])));
        float y = fmaf(fmaf(h, ia, ib), pg[j], pbe[j]);
        y = (y > 0.0f) ? y : 0.2f * y;
        hv[j] = (_Float16)y;
      }
    } else {
#pragma unroll
      for (int j = 0; j < 8; j++) hv[j] = (_Float16)0.f;
    }
    *(f16_8*)&A[n * 136 + o * 8] = hv;
  }
  __syncthreads();

  f32x4 acc[2][8];
#pragma unroll
  for (int a = 0; a < 2; a++)
#pragma unroll
    for (int m = 0; m < 8; m++) acc[a][m] = (f32x4){0.f, 0.f, 0.f, 0.f};

#pragma unroll
  for (int kt = 0; kt < 4; kt++) {
    f16_8 ah[8];
#pragma unroll
    for (int mt = 0; mt < 8; mt++)
      ah[mt] = *(const f16_8*)&A[(mt * 16 + l16) * 136 + kt * 32 + quad * 8];
#pragma unroll
    for (int ni = 0; ni < 2; ni++)
#pragma unroll
      for (int mt = 0; mt < 8; mt++)
        acc[ni][mt] = __builtin_amdgcn_mfma_f32_16x16x32_f16(ah[mt], bh[kt][ni], acc[ni][mt], 0, 0, 0);
  }

#pragma unroll
  for (int ni = 0; ni < 2; ni++) {
    int nt = wv * 2 + ni;
    float m = -3.4e38f;
#pragma unroll
    for (int mt = 0; mt < 8; mt++)
#pragma unroll
      for (int r = 0; r < 4; r++) {
        int row = mt * 16 + quad * 4 + r;
        if (row < NNODES) m = fmaxf(m, acc[ni][mt][r]);
      }
    m = fmaxf(m, __shfl_xor(m, 16, 64));
    m = fmaxf(m, __shfl_xor(m, 32, 64));
    if (quad == 0) {
      int col = nt * 16 + l16;
      z[g * 128 + col] = m + b2[col];
    }
  }
}

// K2: p = z @ W3 + b3 -> fp16 ph; fused deterministic per-block BN partials.
__global__ __launch_bounds__(256) void k2_proj(
    const float* __restrict__ z, const float* __restrict__ W3,
    const float* __restrict__ b3, _Float16* __restrict__ ph,
    float* __restrict__ psum, float* __restrict__ psq) {
  __shared__ float zs[16 * 128];
  __shared__ float reds[8 * 128];
  __shared__ float redq[8 * 128];
  int t = threadIdx.x;
  int rb = blockIdx.x >> 2, cbb = blockIdx.x & 3;
  int gr0 = rb * 16, cc0 = cbb * 128;
  for (int i = t; i < 2048; i += 256) zs[i] = z[gr0 * 128 + i];
  int cg = t & 31, rg = t >> 5;
  int cc = cc0 + cg * 4;
  float4 bb = *(const float4*)&b3[cc];
  float a0[4] = {0.f, 0.f, 0.f, 0.f}, a1[4] = {0.f, 0.f, 0.f, 0.f};
  __syncthreads();

#pragma unroll 8
  for (int k = 0; k < 128; k++) {
    float4 w = *(const float4*)&W3[k * 512 + cc];
    float z0 = zs[rg * 256 + k];
    float z1 = zs[rg * 256 + 128 + k];
    a0[0] = fmaf(z0, w.x, a0[0]); a0[1] = fmaf(z0, w.y, a0[1]);
    a0[2] = fmaf(z0, w.z, a0[2]); a0[3] = fmaf(z0, w.w, a0[3]);
    a1[0] = fmaf(z1, w.x, a1[0]); a1[1] = fmaf(z1, w.y, a1[1]);
    a1[2] = fmaf(z1, w.z, a1[2]); a1[3] = fmaf(z1, w.w, a1[3]);
  }
  int r0 = gr0 + rg * 2;
  f16_4 h0, h1;
  float s[4], q[4];
#pragma unroll
  for (int j = 0; j < 4; j++) {
    float v0 = a0[j] + ((float*)&bb)[j];
    float v1 = a1[j] + ((float*)&bb)[j];
    h0[j] = (_Float16)v0; h1[j] = (_Float16)v1;
    s[j] = v0 + v1;
    q[j] = fmaf(v0, v0, v1 * v1);
  }
  *(f16_4*)&ph[r0 * 512 + cc] = h0;
  *(f16_4*)&ph[(r0 + 1) * 512 + cc] = h1;
#pragma unroll
  for (int j = 0; j < 4; j++) {
    reds[rg * 128 + cg * 4 + j] = s[j];
    redq[rg * 128 + cg * 4 + j] = q[j];
  }
  __syncthreads();
  if (t < 128) {
    float ss = 0.f, qq = 0.f;
#pragma unroll
    for (int r = 0; r < 8; r++) { ss += reds[r * 128 + t]; qq += redq[r * 128 + t]; }
    psum[rb * 512 + cc0 + t] = ss;
    psq[rb * 512 + cc0 + t] = qq;
  }
}

// K3: fixed-order reduce of 256 partials -> BN scale a, shift d
__global__ __launch_bounds__(512) void k3_stats(
    const float* __restrict__ psum, const float* __restrict__ psq,
    const float* __restrict__ bn_g, const float* __restrict__ bn_b,
    float* __restrict__ sa, float* __restrict__ sd) {
  int c = threadIdx.x;
  float s = 0.f, q = 0.f;
#pragma unroll 8
  for (int b = 0; b < 256; b++) {
    s += psum[b * 512 + c];
    q += psq[b * 512 + c];
  }
  float mu = s * (1.0f / 4096.0f);
  float var = fmaxf(q * (1.0f / 4096.0f) - mu * mu, 0.0f);
  float sc = bn_g[c] * rsqrtf(var + 1e-5f);
  sa[c] = sc;
  sd[c] = bn_b[c] - mu * sc;
}

// K4a: 512 blocks (rb64 x cb8), 64 rows x 128 cols; per-block w4p slice = 128 KB.
// Double-buffered T, ONE barrier per kt, prefetch one kt ahead. ~5 blocks/CU.
__global__ __launch_bounds__(256) void k4a_gemm(
    const _Float16* __restrict__ ph, const float* __restrict__ sa,
    const float* __restrict__ sd, const _Float16* __restrict__ w4p,
    const float* __restrict__ b4, float* __restrict__ out,
    float* __restrict__ psn) {
  __shared__ _Float16 T[2][64 * 40];
  __shared__ float sas[512], sds[512];
  __shared__ float rred[4 * 64];
  int t = threadIdx.x;
  int rb = blockIdx.x & 63, cb = blockIdx.x >> 6;
  int lane = t & 63, wv = t >> 6, quad = lane >> 4, l16 = lane & 15;

  for (int i = t; i < 512; i += 256) { sas[i] = sa[i]; sds[i] = sd[i]; }

  int srow = t >> 2, seg8 = (t & 3) * 8;
  const _Float16* prow = &ph[(rb * 64 + srow) * 512];
  f16_8 pa = *(const f16_8*)&prow[seg8];
  f16_8 bfr[2];
#pragma unroll
  for (int ni = 0; ni < 2; ni++)
    bfr[ni] = *(const f16_8*)&w4p[((cb * 8 + wv * 2 + ni) * 64 + lane) * 8];
  __syncthreads();   // sas/sds ready

  {
    f16_8 v;
#pragma unroll
    for (int j = 0; j < 8; j++) {
      float vv = fmaf((float)pa[j], sas[seg8 + j], sds[seg8 + j]);
      v[j] = (_Float16)fmaxf(vv, 0.0f);
    }
    *(f16_8*)&T[0][srow * 40 + seg8] = v;
  }
  __syncthreads();   // T[0] ready

  f32x4 acc[2][4];
#pragma unroll
  for (int a = 0; a < 2; a++)
#pragma unroll
    for (int m = 0; m < 4; m++) acc[a][m] = (f32x4){0.f, 0.f, 0.f, 0.f};

  for (int kt = 0; kt < 16; kt++) {
    int nb = kt + 1;
    f16_8 na;
    if (nb < 16) na = *(const f16_8*)&prow[nb * 32 + seg8];
    f16_8 bc0 = bfr[0], bc1 = bfr[1];
    if (nb < 16) {
#pragma unroll
      for (int ni = 0; ni < 2; ni++)
        bfr[ni] = *(const f16_8*)&w4p[((nb * 64 + cb * 8 + wv * 2 + ni) * 64 + lane) * 8];
    }
    const _Float16* Tb = &T[kt & 1][0];
#pragma unroll
    for (int mt = 0; mt < 4; mt++) {
      f16_8 af = *(const f16_8*)&Tb[(mt * 16 + l16) * 40 + quad * 8];
      acc[0][mt] = __builtin_amdgcn_mfma_f32_16x16x32_f16(af, bc0, acc[0][mt], 0, 0, 0);
      acc[1][mt] = __builtin_amdgcn_mfma_f32_16x16x32_f16(af, bc1, acc[1][mt], 0, 0, 0);
    }
    if (nb < 16) {
      int kc = nb * 32 + seg8;
      f16_8 v;
#pragma unroll
      for (int j = 0; j < 8; j++) {
        float vv = fmaf((float)na[j], sas[kc + j], sds[kc + j]);
        v[j] = (_Float16)fmaxf(vv, 0.0f);
      }
      *(f16_8*)&T[nb & 1][srow * 40 + seg8] = v;
    }
    __syncthreads();   // write(nb) visible; MFMA(kt) reads drained
  }

  // epilogue: +b4, unnormalized store, row sumsq partials
  float rsq[4][4];
#pragma unroll
  for (int mt = 0; mt < 4; mt++)
#pragma unroll
    for (int r = 0; r < 4; r++) rsq[mt][r] = 0.0f;
#pragma unroll
  for (int ni = 0; ni < 2; ni++) {
    int col = cb * 128 + (wv * 2 + ni) * 16 + l16;
    float bv = b4[col];
#pragma unroll
    for (int mt = 0; mt < 4; mt++)
#pragma unroll
      for (int r = 0; r < 4; r++) {
        float v = acc[ni][mt][r] + bv;
        out[(rb * 64 + mt * 16 + quad * 4 + r) * 1024 + col] = v;
        rsq[mt][r] = fmaf(v, v, rsq[mt][r]);
      }
  }
#pragma unroll
  for (int m = 1; m < 16; m <<= 1)
#pragma unroll
    for (int mt = 0; mt < 4; mt++)
#pragma unroll
      for (int r = 0; r < 4; r++) rsq[mt][r] += __shfl_xor(rsq[mt][r], m, 64);
  if (l16 == 0) {
#pragma unroll
    for (int mt = 0; mt < 4; mt++)
#pragma unroll
      for (int r = 0; r < 4; r++)
        rred[wv * 64 + mt * 16 + quad * 4 + r] = rsq[mt][r];
  }
  __syncthreads();
  if (t < 64) {
    float s = rred[t] + rred[64 + t] + rred[128 + t] + rred[192 + t];
    psn[cb * 4096 + rb * 64 + t] = s;
  }
}

// K4b: in-place L2 normalize of out, 4 rows/block.
__global__ __launch_bounds__(256) void k4b_norm(
    float* __restrict__ out, const float* __restrict__ psn) {
  int t = threadIdx.x;
  int row = blockIdx.x * 4 + (t >> 6);
  float s = 0.f;
#pragma unroll
  for (int cb = 0; cb < 8; cb++) s += psn[cb * 4096 + row];
  float inv = 1.0f / fmaxf(sqrtf(s), 1e-12f);
  int c0 = (t & 63) * 4;
#pragma unroll
  for (int it = 0; it < 4; it++) {
    float4 v = *(const float4*)&out[row * 1024 + it * 256 + c0];
    v.x *= inv; v.y *= inv; v.z *= inv; v.w *= inv;
    *(float4*)&out[row * 1024 + it * 256 + c0] = v;
  }
}

extern "C" void kernel_launch(void* const* d_in, const int* in_sizes, int n_in,
                              void* d_out, int out_size, void* d_ws, size_t ws_size,
                              hipStream_t stream) {
  const float* x   = (const float*)d_in[0];
  const float* roi = (const float*)d_in[1];
  const float* W1  = (const float*)d_in[2];
  const float* b1  = (const float*)d_in[3];
  const float* gng = (const float*)d_in[4];
  const float* gnb = (const float*)d_in[5];
  const float* W2  = (const float*)d_in[6];
  const float* b2  = (const float*)d_in[7];
  const float* W3  = (const float*)d_in[8];
  const float* b3  = (const float*)d_in[9];
  const float* bng = (const float*)d_in[10];
  const float* bnb = (const float*)d_in[11];
  const float* W4  = (const float*)d_in[12];
  const float* b4  = (const float*)d_in[13];
  float* out = (float*)d_out;

  char* ws = (char*)d_ws;
  float*    z    = (float*)(ws + Z_OFF);
  _Float16* ph   = (_Float16*)(ws + PH_OFF);
  float*    psum = (float*)(ws + PSUM_OFF);
  float*    psq  = (float*)(ws + PSQ_OFF);
  float*    psn  = (float*)(ws + PSN_OFF);
  float*    gc   = (float*)(ws + GC_OFF);
  float*    sa   = (float*)(ws + SA_OFF);
  float*    sd   = (float*)(ws + SD_OFF);
  _Float16* w2p  = (_Float16*)(ws + W2P_OFF);
  _Float16* w4p  = (_Float16*)(ws + W4P_OFF);

  k0_prep<<<265, 256, 0, stream>>>(W2, W4, W1, b1, w2p, w4p, gc);
  k1_nodenet<<<NGRAPH, 256, 0, stream>>>(x, roi, W1, b1, gng, gnb, w2p, b2, gc, z);
  k2_proj<<<1024, 256, 0, stream>>>(z, W3, b3, ph, psum, psq);
  k3_stats<<<1, 512, 0, stream>>>(psum, psq, bng, bnb, sa, sd);
  k4a_gemm<<<512, 256, 0, stream>>>(ph, sa, sd, w4p, b4, out, psn);
  k4b_norm<<<1024, 256, 0, stream>>>(out, psn);
}